// Round 6
// baseline (639.472 us; speedup 1.0000x reference)
//
#include <hip/hip_runtime.h>

typedef __attribute__((ext_vector_type(8))) short short8;
typedef __attribute__((ext_vector_type(4))) short short4v;
typedef __attribute__((ext_vector_type(4))) float floatx4;

__device__ __forceinline__ short f2bf(float x) {
    unsigned u = __builtin_bit_cast(unsigned, x);
    u = (u + 0x7FFFu + ((u >> 16) & 1u)) >> 16;   // RNE
    return (short)u;
}

// Pack edge weights into exact MFMA B-fragment order (bf16):
// short index = ((((ks*4 + quad)*8 + t)*16 + m)*8 + j)
//   value = w[k*128 + n],  k = ks*32 + quad*8 + j,  n = t*16 + m.
__global__ __launch_bounds__(256) void prep_weights(
    const float* ew1, const float* ew2, short* w1P, short* w2P)
{
    int idx = blockIdx.x * 256 + threadIdx.x;
    if (idx < 49152) {                 // layer1: K=384 -> ks 0..11
        int j = idx & 7, mm = (idx >> 3) & 15, t = (idx >> 7) & 7,
            quad = (idx >> 10) & 3, ks = idx >> 12;
        int k = ks * 32 + quad * 8 + j;
        int n = t * 16 + mm;
        w1P[idx] = f2bf(ew1[k * 128 + n]);
    } else if (idx < 65536) {          // layer2: K=128 -> ks 0..3
        int i = idx - 49152;
        int j = i & 7, mm = (i >> 3) & 15, t = (i >> 7) & 7,
            quad = (i >> 10) & 3, ks = (i >> 12) & 3;
        int k = ks * 32 + quad * 8 + j;
        int n = t * 16 + mm;
        w2P[i] = f2bf(ew2[k * 128 + n]);
    }
}

// ---- CSR build: histogram -> wave-aggregated range allocation -> fill ----
// ~650K int atomics total; bucket order irrelevant for a segment-sum, so
// ranges are allocated with one global atomic per wave (no scan, no sort).

__global__ __launch_bounds__(256) void csr_hist(
    const int* recv, int* counts, int E)
{
    int idx = blockIdx.x * 256 + threadIdx.x;
    if (idx < E) atomicAdd(&counts[recv[idx]], 1);
}

__global__ __launch_bounds__(256) void csr_alloc(
    const int* counts, int* startA, int* cursor, int* gctr, int N)
{
    int idx = blockIdx.x * 256 + threadIdx.x;
    int lane = threadIdx.x & 63;
    int v = (idx < N) ? counts[idx] : 0;
    int pre = v;                           // wave-inclusive prefix sum
#pragma unroll
    for (int off = 1; off < 64; off <<= 1) {
        int t = __shfl_up(pre, off);
        if (lane >= off) pre += t;
    }
    int wsum = __shfl(pre, 63);
    int base = 0;
    if (lane == 63) base = atomicAdd(gctr, wsum);   // 1 atomic / 64 nodes
    base = __shfl(base, 63);
    if (idx < N) {
        int s = base + pre - v;            // exclusive prefix within wave
        startA[idx] = s;
        cursor[idx] = s;
    }
}

__global__ __launch_bounds__(256) void csr_fill(
    const int* recv, int* cursor, int* eidx, int E)
{
    int idx = blockIdx.x * 256 + threadIdx.x;
    if (idx < E) {
        int pos = atomicAdd(&cursor[recv[idx]], 1);
        eidx[pos] = idx;
    }
}

// Node MLP + LN, exact f32 VALU path, CSR gather fused in.
// (unchanged from round 4 — dropped out of top-5 at <188us)
__global__ __launch_bounds__(256) void node_mlp_valu(
    const float* node_f, const float* edge_f,
    const int* counts, const int* startA, const int* eidx,
    const float* w1, const float* b1, const float* w2, const float* b2,
    const float* g, const float* bvec,
    float* out, short* nodes_bf, int N)
{
    const int grp = threadIdx.x >> 5;      // 8 groups of 32 lanes
    const int sub = threadIdx.x & 31;
    const int c0 = sub * 4;
    const int rbase = grp * 4;             // rows within block
    const long grow0 = (long)blockIdx.x * 32;

    __shared__ float xs[32][256];          // 32 KB; hs aliases xs[16..31]
    float (*hs)[128] = reinterpret_cast<float(*)[128]>(&xs[16][0]);

    // Stage node features (cols 0..127) cooperatively.
    for (int i = threadIdx.x; i < 1024; i += 256) {
        int rr = i >> 5, q = i & 31;
        long grow = grow0 + rr; if (grow >= N) grow = N - 1;
        *reinterpret_cast<floatx4*>(&xs[rr][q * 4]) =
            *reinterpret_cast<const floatx4*>(node_f + grow * 128 + q * 4);
    }

    // Gather-aggregate incident edges (cols 128..255).
    int cnt[4], st[4], eids[4];
#pragma unroll
    for (int r = 0; r < 4; r++) {
        long row = grow0 + rbase + r;
        cnt[r] = 0; st[r] = 0;
        if (row < N) { cnt[r] = counts[row]; st[r] = startA[row]; }
        eids[r] = (sub < cnt[r]) ? eidx[st[r] + sub] : 0;
    }
    floatx4 s[4];
#pragma unroll
    for (int r = 0; r < 4; r++) s[r] = (floatx4){0.f, 0.f, 0.f, 0.f};

    int mx = max(max(cnt[0], cnt[1]), max(cnt[2], cnt[3]));
    int mxc = min(mx, 32);
#pragma unroll 2
    for (int p = 0; p < mxc; p++) {
#pragma unroll
        for (int r = 0; r < 4; r++) {
            if (p < cnt[r]) {
                int eid = __shfl(eids[r], p, 32);
                s[r] += *reinterpret_cast<const floatx4*>(
                    edge_f + (size_t)eid * 128 + c0);
            }
        }
    }
    // Rare tail (degree > 32): direct loads.
    if (mx > 32) {
#pragma unroll
        for (int r = 0; r < 4; r++)
            for (int p = 32; p < cnt[r]; p++) {
                int eid = eidx[st[r] + p];
                s[r] += *reinterpret_cast<const floatx4*>(
                    edge_f + (size_t)eid * 128 + c0);
            }
    }
#pragma unroll
    for (int r = 0; r < 4; r++)
        *reinterpret_cast<floatx4*>(&xs[rbase + r][128 + c0]) = s[r];
    __syncthreads();

    float acc[4][4] = {};
    for (int k = 0; k < 256; k += 4) {
        floatx4 x0 = *reinterpret_cast<const floatx4*>(&xs[rbase + 0][k]);
        floatx4 x1 = *reinterpret_cast<const floatx4*>(&xs[rbase + 1][k]);
        floatx4 x2 = *reinterpret_cast<const floatx4*>(&xs[rbase + 2][k]);
        floatx4 x3 = *reinterpret_cast<const floatx4*>(&xs[rbase + 3][k]);
#pragma unroll
        for (int kk = 0; kk < 4; kk++) {
            floatx4 w = *reinterpret_cast<const floatx4*>(
                w1 + (size_t)(k + kk) * 128 + c0);
#pragma unroll
            for (int j = 0; j < 4; j++) {
                acc[0][j] += x0[kk] * w[j];
                acc[1][j] += x1[kk] * w[j];
                acc[2][j] += x2[kk] * w[j];
                acc[3][j] += x3[kk] * w[j];
            }
        }
    }
    __syncthreads();                       // all xs reads done before alias write
    {
        floatx4 bb = *reinterpret_cast<const floatx4*>(b1 + c0);
#pragma unroll
        for (int r = 0; r < 4; r++) {
            floatx4 h;
#pragma unroll
            for (int j = 0; j < 4; j++) h[j] = acc[r][j] + bb[j];
            *reinterpret_cast<floatx4*>(&hs[rbase + r][c0]) = h;
        }
    }
    __syncthreads();

    float acc2[4][4] = {};
    for (int k = 0; k < 128; k += 4) {
        floatx4 h0 = *reinterpret_cast<const floatx4*>(&hs[rbase + 0][k]);
        floatx4 h1 = *reinterpret_cast<const floatx4*>(&hs[rbase + 1][k]);
        floatx4 h2 = *reinterpret_cast<const floatx4*>(&hs[rbase + 2][k]);
        floatx4 h3 = *reinterpret_cast<const floatx4*>(&hs[rbase + 3][k]);
#pragma unroll
        for (int kk = 0; kk < 4; kk++) {
            floatx4 w = *reinterpret_cast<const floatx4*>(
                w2 + (size_t)(k + kk) * 128 + c0);
#pragma unroll
            for (int j = 0; j < 4; j++) {
                acc2[0][j] += h0[kk] * w[j];
                acc2[1][j] += h1[kk] * w[j];
                acc2[2][j] += h2[kk] * w[j];
                acc2[3][j] += h3[kk] * w[j];
            }
        }
    }

    floatx4 bb2 = *reinterpret_cast<const floatx4*>(b2 + c0);
    floatx4 gg  = *reinterpret_cast<const floatx4*>(g + c0);
    floatx4 bv  = *reinterpret_cast<const floatx4*>(bvec + c0);
    float vals[4][4];
    float s1[4] = {}, s2[4] = {};
#pragma unroll
    for (int r = 0; r < 4; r++) {
#pragma unroll
        for (int j = 0; j < 4; j++) {
            float v = acc2[r][j] + bb2[j];
            vals[r][j] = v; s1[r] += v; s2[r] += v * v;
        }
    }
#pragma unroll
    for (int off = 1; off < 32; off <<= 1) {
#pragma unroll
        for (int r = 0; r < 4; r++) {
            s1[r] += __shfl_xor(s1[r], off, 32);
            s2[r] += __shfl_xor(s2[r], off, 32);
        }
    }
#pragma unroll
    for (int r = 0; r < 4; r++) {
        long row = grow0 + rbase + r;
        if (row < N) {
            const float mu = s1[r] * (1.f / 128.f);
            const float var = s2[r] * (1.f / 128.f) - mu * mu;
            const float rstd = rsqrtf(var + 1e-5f);
            floatx4 o; short4v ob;
#pragma unroll
            for (int j = 0; j < 4; j++) {
                o[j] = (vals[r][j] - mu) * rstd * gg[j] + bv[j];
                ob[j] = f2bf(o[j]);
            }
            *reinterpret_cast<floatx4*>(out + row * 128 + c0) = o;
            *reinterpret_cast<short4v*>(nodes_bf + row * 128 + c0) = ob;
        }
    }
}

// Edge MLP + LN via MFMA 16x16x32 bf16.
// Round-5 diagnosis: VGPR_Count=44 proved the compiler sank the A-preloads
// back to their uses (a[12] alone needs 48 VGPRs) -> gathers serialized.
// Fix: issue all 16 A-loads (feat first = oldest in vmcnt order, then the
// 8 random gathers), then sched_barrier(0) pins them before any consumer.
// One combined vmcnt drain (~1 latency) replaces ~6-8 serial latencies.
__global__ __launch_bounds__(256, 4) void edge_mlp_mfma(
    const float* feat, const short* nodes_bf,
    const int* senders, const int* receivers,
    const short8* w1P, const short8* w2P,
    const float* b1, const float* b2, const float* g, const float* bvec,
    float* out, int nrows)
{
    const int wave = threadIdx.x >> 6;
    const int lane = threadIdx.x & 63;
    const int m = lane & 15;        // A-row / C-col within tile
    const int quad = lane >> 4;     // k-group / C-row-group

    const int row0 = blockIdx.x * 64 + wave * 16;
    const bool active = (row0 < nrows);
    int row = row0 + m;
    if (row >= nrows) row = nrows - 1;     // clamp for safe loads

    const int s_idx = senders[row];
    const int r_idx = receivers[row];

    const float* pf = feat + (size_t)row * 128 + quad * 8;
    const short* ps = nodes_bf + (size_t)s_idx * 128 + quad * 8;
    const short* pr = nodes_bf + (size_t)r_idx * 128 + quad * 8;

    // Streaming feat loads first (oldest in the in-order vmcnt queue)...
    floatx4 ff[8];
#pragma unroll
    for (int ks = 0; ks < 4; ks++) {
        ff[2 * ks]     = *reinterpret_cast<const floatx4*>(pf + ks * 32);
        ff[2 * ks + 1] = *reinterpret_cast<const floatx4*>(pf + ks * 32 + 4);
    }
    // ...then the 8 random-address node gathers. All 16 loads in flight.
    short8 a[8];
#pragma unroll
    for (int ks = 0; ks < 4; ks++)
        a[ks] = *reinterpret_cast<const short8*>(ps + ks * 32);
#pragma unroll
    for (int ks = 0; ks < 4; ks++)
        a[4 + ks] = *reinterpret_cast<const short8*>(pr + ks * 32);
    // Pin: the scheduler may not sink any of the above loads past here.
    __builtin_amdgcn_sched_barrier(0);

    // Convert feat to bf16 (waits only the 8 oldest loads; gathers fly on).
    short8 fa[4];
#pragma unroll
    for (int ks = 0; ks < 4; ks++) {
        short8 t;
#pragma unroll
        for (int j = 0; j < 4; j++) {
            t[j]     = f2bf(ff[2 * ks][j]);
            t[4 + j] = f2bf(ff[2 * ks + 1][j]);
        }
        fa[ks] = t;
    }

    const floatx4 zero4 = {0.f, 0.f, 0.f, 0.f};
    floatx4 acc1[8];
#pragma unroll
    for (int t = 0; t < 8; t++) acc1[t] = zero4;

    const short8* wb1 = w1P + quad * 128 + m;   // short8 units
    __builtin_amdgcn_s_setprio(1);
#pragma unroll
    for (int ks = 0; ks < 8; ks++) {            // k = 0..255 (sender | recv)
#pragma unroll
        for (int t = 0; t < 8; t++)
            acc1[t] = __builtin_amdgcn_mfma_f32_16x16x32_bf16(
                a[ks], wb1[ks * 512 + t * 16], acc1[t], 0, 0, 0);
    }
#pragma unroll
    for (int ks = 0; ks < 4; ks++) {            // k = 256..383 (feat)
#pragma unroll
        for (int t = 0; t < 8; t++)
            acc1[t] = __builtin_amdgcn_mfma_f32_16x16x32_bf16(
                fa[ks], wb1[(8 + ks) * 512 + t * 16], acc1[t], 0, 0, 0);
    }
    __builtin_amdgcn_s_setprio(0);

    // h = layer1 + b1 -> LDS (bf16): C-layout -> A-layout round trip
    __shared__ short lds_h[4][16][136];
#pragma unroll
    for (int t = 0; t < 8; t++) {
        const int col = t * 16 + m;
        const float bias = b1[col];
#pragma unroll
        for (int r = 0; r < 4; r++)
            lds_h[wave][quad * 4 + r][col] = f2bf(acc1[t][r] + bias);
    }
    __syncthreads();

    floatx4 acc2[8];
#pragma unroll
    for (int t = 0; t < 8; t++) acc2[t] = zero4;
    const short8* wb2 = w2P + quad * 128 + m;
    __builtin_amdgcn_s_setprio(1);
#pragma unroll
    for (int ks = 0; ks < 4; ks++) {
        const int k0 = ks * 32 + quad * 8;
        short8 ah = *reinterpret_cast<const short8*>(&lds_h[wave][m][k0]);
#pragma unroll
        for (int t = 0; t < 8; t++)
            acc2[t] = __builtin_amdgcn_mfma_f32_16x16x32_bf16(
                ah, wb2[ks * 512 + t * 16], acc2[t], 0, 0, 0);
    }
    __builtin_amdgcn_s_setprio(0);

    // bias2 + LayerNorm over each row's 128 cols
    float vals[8][4];
    float s1[4] = {0.f, 0.f, 0.f, 0.f}, s2[4] = {0.f, 0.f, 0.f, 0.f};
#pragma unroll
    for (int t = 0; t < 8; t++) {
        const float bias = b2[t * 16 + m];
#pragma unroll
        for (int r = 0; r < 4; r++) {
            float v = acc2[t][r] + bias;
            vals[t][r] = v; s1[r] += v; s2[r] += v * v;
        }
    }
#pragma unroll
    for (int off = 1; off < 16; off <<= 1) {
#pragma unroll
        for (int r = 0; r < 4; r++) {
            s1[r] += __shfl_xor(s1[r], off);
            s2[r] += __shfl_xor(s2[r], off);
        }
    }
    if (active) {
#pragma unroll
        for (int r = 0; r < 4; r++) {
            const float mu = s1[r] * (1.f / 128.f);
            const float var = s2[r] * (1.f / 128.f) - mu * mu;
            const float rstd = rsqrtf(var + 1e-5f);
            const int orow = row0 + quad * 4 + r;
#pragma unroll
            for (int t = 0; t < 8; t++) {
                const int col = t * 16 + m;
                out[(size_t)orow * 128 + col] =
                    (vals[t][r] - mu) * rstd * g[col] + bvec[col];
            }
        }
    }
}

extern "C" void kernel_launch(void* const* d_in, const int* in_sizes, int n_in,
                              void* d_out, int out_size, void* d_ws, size_t ws_size,
                              hipStream_t stream)
{
    const float* node_f = (const float*)d_in[0];
    const float* edge_f = (const float*)d_in[1];
    const int* senders   = (const int*)d_in[2];
    const int* receivers = (const int*)d_in[3];
    const float* nw1 = (const float*)d_in[4];
    const float* nb1 = (const float*)d_in[5];
    const float* nw2 = (const float*)d_in[6];
    const float* nb2 = (const float*)d_in[7];
    const float* ng  = (const float*)d_in[8];
    const float* nbb = (const float*)d_in[9];
    const float* ew1 = (const float*)d_in[10];
    const float* eb1 = (const float*)d_in[11];
    const float* ew2 = (const float*)d_in[12];
    const float* eb2 = (const float*)d_in[13];
    const float* eg  = (const float*)d_in[14];
    const float* ebb = (const float*)d_in[15];

    const int N = in_sizes[0] / 128;
    const int E = in_sizes[2];

    // ws layout (ints first): counts[N] | gctr[64] | startA[N] | cursor[N] |
    // eidx[E] | nodes_bf[N*128 bf16] | w1P | w2P.   ~14.7 MB total.
    char* ws = (char*)d_ws;
    int* counts = (int*)ws;
    int* gctr   = counts + N;
    int* startA = gctr + 64;
    int* cursor = startA + N;
    int* eidx   = cursor + N;
    size_t int_bytes = ((size_t)(3 * N + 64) + (size_t)E) * 4;
    int_bytes = (int_bytes + 15) & ~(size_t)15;          // 16B align
    short* nodes_bf = (short*)(ws + int_bytes);
    short* w1P = nodes_bf + (size_t)N * 128;
    short* w2P = w1P + 49152;

    float* out_nodes = (float*)d_out;
    float* out_edges = out_nodes + (size_t)N * 128;

    hipMemsetAsync(counts, 0, (size_t)(N + 64) * 4, stream);  // counts + gctr
    prep_weights<<<256, 256, 0, stream>>>(ew1, ew2, w1P, w2P);

    csr_hist<<<(E + 255) / 256, 256, 0, stream>>>(receivers, counts, E);
    csr_alloc<<<(N + 255) / 256, 256, 0, stream>>>(counts, startA, cursor, gctr, N);
    csr_fill<<<(E + 255) / 256, 256, 0, stream>>>(receivers, cursor, eidx, E);

    node_mlp_valu<<<(N + 31) / 32, 256, 0, stream>>>(
        node_f, edge_f, counts, startA, eidx,
        nw1, nb1, nw2, nb2, ng, nbb, out_nodes, nodes_bf, N);

    edge_mlp_mfma<<<(E + 63) / 64, 256, 0, stream>>>(
        edge_f, nodes_bf, senders, receivers,
        (const short8*)w1P, (const short8*)w2P,
        eb1, eb2, eg, ebb, out_edges, E);
}

// Round 7
// 580.999 us; speedup vs baseline: 1.1006x; 1.1006x over previous
//
#include <hip/hip_runtime.h>

typedef __attribute__((ext_vector_type(8))) short short8;
typedef __attribute__((ext_vector_type(4))) short short4v;
typedef __attribute__((ext_vector_type(4))) float floatx4;

__device__ __forceinline__ short f2bf(float x) {
    unsigned u = __builtin_bit_cast(unsigned, x);
    u = (u + 0x7FFFu + ((u >> 16) & 1u)) >> 16;   // RNE
    return (short)u;
}

// Async 16B/lane global->LDS copy. Per-lane GLOBAL address; LDS dest is
// wave-uniform base + lane*16 (m104/m173 semantics). Void result => the
// scheduler cannot sink it; all issued copies stay concurrently in flight.
__device__ __forceinline__ void gload_lds16(const void* g, void* l) {
    __builtin_amdgcn_global_load_lds(
        (const __attribute__((address_space(1))) void*)g,
        (__attribute__((address_space(3))) void*)l, 16, 0, 0);
}

// Pack edge weights into exact MFMA B-fragment order (bf16):
// short index = ((((ks*4 + quad)*8 + t)*16 + m)*8 + j)
//   value = w[k*128 + n],  k = ks*32 + quad*8 + j,  n = t*16 + m.
__global__ __launch_bounds__(256) void prep_weights(
    const float* ew1, const float* ew2, short* w1P, short* w2P)
{
    int idx = blockIdx.x * 256 + threadIdx.x;
    if (idx < 49152) {                 // layer1: K=384 -> ks 0..11
        int j = idx & 7, mm = (idx >> 3) & 15, t = (idx >> 7) & 7,
            quad = (idx >> 10) & 3, ks = idx >> 12;
        int k = ks * 32 + quad * 8 + j;
        int n = t * 16 + mm;
        w1P[idx] = f2bf(ew1[k * 128 + n]);
    } else if (idx < 65536) {          // layer2: K=128 -> ks 0..3
        int i = idx - 49152;
        int j = i & 7, mm = (i >> 3) & 15, t = (i >> 7) & 7,
            quad = (i >> 10) & 3, ks = (i >> 12) & 3;
        int k = ks * 32 + quad * 8 + j;
        int n = t * 16 + mm;
        w2P[i] = f2bf(ew2[k * 128 + n]);
    }
}

// ---- CSR build: histogram -> wave-aggregated range allocation -> fill ----
__global__ __launch_bounds__(256) void csr_hist(
    const int* recv, int* counts, int E)
{
    int idx = blockIdx.x * 256 + threadIdx.x;
    if (idx < E) atomicAdd(&counts[recv[idx]], 1);
}

__global__ __launch_bounds__(256) void csr_alloc(
    const int* counts, int* startA, int* cursor, int* gctr, int N)
{
    int idx = blockIdx.x * 256 + threadIdx.x;
    int lane = threadIdx.x & 63;
    int v = (idx < N) ? counts[idx] : 0;
    int pre = v;                           // wave-inclusive prefix sum
#pragma unroll
    for (int off = 1; off < 64; off <<= 1) {
        int t = __shfl_up(pre, off);
        if (lane >= off) pre += t;
    }
    int wsum = __shfl(pre, 63);
    int base = 0;
    if (lane == 63) base = atomicAdd(gctr, wsum);   // 1 atomic / 64 nodes
    base = __shfl(base, 63);
    if (idx < N) {
        int s = base + pre - v;            // exclusive prefix within wave
        startA[idx] = s;
        cursor[idx] = s;
    }
}

__global__ __launch_bounds__(256) void csr_fill(
    const int* recv, int* cursor, int* eidx, int E)
{
    int idx = blockIdx.x * 256 + threadIdx.x;
    if (idx < E) {
        int pos = atomicAdd(&cursor[recv[idx]], 1);
        eidx[pos] = idx;
    }
}

// Node MLP + LN, exact f32 VALU path, CSR gather fused in.
// (unchanged — dropped out of top-5 at <188us)
__global__ __launch_bounds__(256) void node_mlp_valu(
    const float* node_f, const float* edge_f,
    const int* counts, const int* startA, const int* eidx,
    const float* w1, const float* b1, const float* w2, const float* b2,
    const float* g, const float* bvec,
    float* out, short* nodes_bf, int N)
{
    const int grp = threadIdx.x >> 5;      // 8 groups of 32 lanes
    const int sub = threadIdx.x & 31;
    const int c0 = sub * 4;
    const int rbase = grp * 4;             // rows within block
    const long grow0 = (long)blockIdx.x * 32;

    __shared__ float xs[32][256];          // 32 KB; hs aliases xs[16..31]
    float (*hs)[128] = reinterpret_cast<float(*)[128]>(&xs[16][0]);

    // Stage node features (cols 0..127) cooperatively.
    for (int i = threadIdx.x; i < 1024; i += 256) {
        int rr = i >> 5, q = i & 31;
        long grow = grow0 + rr; if (grow >= N) grow = N - 1;
        *reinterpret_cast<floatx4*>(&xs[rr][q * 4]) =
            *reinterpret_cast<const floatx4*>(node_f + grow * 128 + q * 4);
    }

    // Gather-aggregate incident edges (cols 128..255).
    int cnt[4], st[4], eids[4];
#pragma unroll
    for (int r = 0; r < 4; r++) {
        long row = grow0 + rbase + r;
        cnt[r] = 0; st[r] = 0;
        if (row < N) { cnt[r] = counts[row]; st[r] = startA[row]; }
        eids[r] = (sub < cnt[r]) ? eidx[st[r] + sub] : 0;
    }
    floatx4 s[4];
#pragma unroll
    for (int r = 0; r < 4; r++) s[r] = (floatx4){0.f, 0.f, 0.f, 0.f};

    int mx = max(max(cnt[0], cnt[1]), max(cnt[2], cnt[3]));
    int mxc = min(mx, 32);
#pragma unroll 2
    for (int p = 0; p < mxc; p++) {
#pragma unroll
        for (int r = 0; r < 4; r++) {
            if (p < cnt[r]) {
                int eid = __shfl(eids[r], p, 32);
                s[r] += *reinterpret_cast<const floatx4*>(
                    edge_f + (size_t)eid * 128 + c0);
            }
        }
    }
    // Rare tail (degree > 32): direct loads.
    if (mx > 32) {
#pragma unroll
        for (int r = 0; r < 4; r++)
            for (int p = 32; p < cnt[r]; p++) {
                int eid = eidx[st[r] + p];
                s[r] += *reinterpret_cast<const floatx4*>(
                    edge_f + (size_t)eid * 128 + c0);
            }
    }
#pragma unroll
    for (int r = 0; r < 4; r++)
        *reinterpret_cast<floatx4*>(&xs[rbase + r][128 + c0]) = s[r];
    __syncthreads();

    float acc[4][4] = {};
    for (int k = 0; k < 256; k += 4) {
        floatx4 x0 = *reinterpret_cast<const floatx4*>(&xs[rbase + 0][k]);
        floatx4 x1 = *reinterpret_cast<const floatx4*>(&xs[rbase + 1][k]);
        floatx4 x2 = *reinterpret_cast<const floatx4*>(&xs[rbase + 2][k]);
        floatx4 x3 = *reinterpret_cast<const floatx4*>(&xs[rbase + 3][k]);
#pragma unroll
        for (int kk = 0; kk < 4; kk++) {
            floatx4 w = *reinterpret_cast<const floatx4*>(
                w1 + (size_t)(k + kk) * 128 + c0);
#pragma unroll
            for (int j = 0; j < 4; j++) {
                acc[0][j] += x0[kk] * w[j];
                acc[1][j] += x1[kk] * w[j];
                acc[2][j] += x2[kk] * w[j];
                acc[3][j] += x3[kk] * w[j];
            }
        }
    }
    __syncthreads();                       // all xs reads done before alias write
    {
        floatx4 bb = *reinterpret_cast<const floatx4*>(b1 + c0);
#pragma unroll
        for (int r = 0; r < 4; r++) {
            floatx4 h;
#pragma unroll
            for (int j = 0; j < 4; j++) h[j] = acc[r][j] + bb[j];
            *reinterpret_cast<floatx4*>(&hs[rbase + r][c0]) = h;
        }
    }
    __syncthreads();

    float acc2[4][4] = {};
    for (int k = 0; k < 128; k += 4) {
        floatx4 h0 = *reinterpret_cast<const floatx4*>(&hs[rbase + 0][k]);
        floatx4 h1 = *reinterpret_cast<const floatx4*>(&hs[rbase + 1][k]);
        floatx4 h2 = *reinterpret_cast<const floatx4*>(&hs[rbase + 2][k]);
        floatx4 h3 = *reinterpret_cast<const floatx4*>(&hs[rbase + 3][k]);
#pragma unroll
        for (int kk = 0; kk < 4; kk++) {
            floatx4 w = *reinterpret_cast<const floatx4*>(
                w2 + (size_t)(k + kk) * 128 + c0);
#pragma unroll
            for (int j = 0; j < 4; j++) {
                acc2[0][j] += h0[kk] * w[j];
                acc2[1][j] += h1[kk] * w[j];
                acc2[2][j] += h2[kk] * w[j];
                acc2[3][j] += h3[kk] * w[j];
            }
        }
    }

    floatx4 bb2 = *reinterpret_cast<const floatx4*>(b2 + c0);
    floatx4 gg  = *reinterpret_cast<const floatx4*>(g + c0);
    floatx4 bv  = *reinterpret_cast<const floatx4*>(bvec + c0);
    float vals[4][4];
    float s1[4] = {}, s2[4] = {};
#pragma unroll
    for (int r = 0; r < 4; r++) {
#pragma unroll
        for (int j = 0; j < 4; j++) {
            float v = acc2[r][j] + bb2[j];
            vals[r][j] = v; s1[r] += v; s2[r] += v * v;
        }
    }
#pragma unroll
    for (int off = 1; off < 32; off <<= 1) {
#pragma unroll
        for (int r = 0; r < 4; r++) {
            s1[r] += __shfl_xor(s1[r], off, 32);
            s2[r] += __shfl_xor(s2[r], off, 32);
        }
    }
#pragma unroll
    for (int r = 0; r < 4; r++) {
        long row = grow0 + rbase + r;
        if (row < N) {
            const float mu = s1[r] * (1.f / 128.f);
            const float var = s2[r] * (1.f / 128.f) - mu * mu;
            const float rstd = rsqrtf(var + 1e-5f);
            floatx4 o; short4v ob;
#pragma unroll
            for (int j = 0; j < 4; j++) {
                o[j] = (vals[r][j] - mu) * rstd * gg[j] + bv[j];
                ob[j] = f2bf(o[j]);
            }
            *reinterpret_cast<floatx4*>(out + row * 128 + c0) = o;
            *reinterpret_cast<short4v*>(nodes_bf + row * 128 + c0) = ob;
        }
    }
}

// Edge MLP + LN via MFMA 16x16x32 bf16.
// Rounds 5/6 proved the scheduler sinks any VGPR-result load to its use
// (VGPR 44/56), serializing the 16 node gathers. Fix: route the gathers
// through global_load_lds (void, unsinkable) -> all 8 in flight, one
// vmcnt(0) drain, readback via conflict-free lane*16 ds_read_b128.
// Staging (8KB/wave) aliases the wave-private lds_h region; 32KB/block.
__global__ __launch_bounds__(256) void edge_mlp_mfma(
    const float* feat, const short* nodes_bf,
    const int* senders, const int* receivers,
    const short8* w1P, const short8* w2P,
    const float* b1, const float* b2, const float* g, const float* bvec,
    float* out, int nrows)
{
    const int wave = threadIdx.x >> 6;
    const int lane = threadIdx.x & 63;
    const int m = lane & 15;        // A-row / C-col within tile
    const int quad = lane >> 4;     // k-group / C-row-group

    __shared__ char smem[4][8192];   // per-wave staging / lds_h (aliased)
    char* wbase = smem[wave];

    const int row0 = blockIdx.x * 64 + wave * 16;
    const bool active = (row0 < nrows);
    int row = row0 + m;
    if (row >= nrows) row = nrows - 1;     // clamp for safe loads

    const int s_idx = senders[row];
    const int r_idx = receivers[row];

    const float* pf = feat + (size_t)row * 128 + quad * 8;
    const short* ps = nodes_bf + (size_t)s_idx * 128 + quad * 8;
    const short* pr = nodes_bf + (size_t)r_idx * 128 + quad * 8;

    // Streaming feat loads (register results; compiler may sink to the
    // conversion — harmless, they are issued before/with the gathers).
    floatx4 ff[8];
#pragma unroll
    for (int ks = 0; ks < 4; ks++) {
        ff[2 * ks]     = *reinterpret_cast<const floatx4*>(pf + ks * 32);
        ff[2 * ks + 1] = *reinterpret_cast<const floatx4*>(pf + ks * 32 + 4);
    }

    // 8 async random-address gathers, all concurrently in flight.
    // Slice ks lands at wbase + ks*1024 + lane*16.
#pragma unroll
    for (int ks = 0; ks < 4; ks++)
        gload_lds16(ps + ks * 32, wbase + ks * 1024);
#pragma unroll
    for (int ks = 0; ks < 4; ks++)
        gload_lds16(pr + ks * 32, wbase + (4 + ks) * 1024);

    // Convert feat to bf16 while the gathers fly.
    short8 fa[4];
#pragma unroll
    for (int ks = 0; ks < 4; ks++) {
        short8 t;
#pragma unroll
        for (int j = 0; j < 4; j++) {
            t[j]     = f2bf(ff[2 * ks][j]);
            t[4 + j] = f2bf(ff[2 * ks + 1][j]);
        }
        fa[ks] = t;
    }

    // Single combined drain of the staging copies (one max-latency instead
    // of 8 serial ones), then keep dependent ds_reads below it.
    asm volatile("s_waitcnt vmcnt(0)" ::: "memory");
    __builtin_amdgcn_sched_barrier(0);

    const floatx4 zero4 = {0.f, 0.f, 0.f, 0.f};
    floatx4 acc1[8];
#pragma unroll
    for (int t = 0; t < 8; t++) acc1[t] = zero4;

    const short8* stg = reinterpret_cast<const short8*>(wbase);
    const short8* wb1 = w1P + quad * 128 + m;   // short8 units
#pragma unroll
    for (int ks = 0; ks < 8; ks++) {            // k = 0..255 (sender | recv)
        short8 av = stg[ks * 64 + lane];        // conflict-free ds_read_b128
#pragma unroll
        for (int t = 0; t < 8; t++)
            acc1[t] = __builtin_amdgcn_mfma_f32_16x16x32_bf16(
                av, wb1[ks * 512 + t * 16], acc1[t], 0, 0, 0);
    }
#pragma unroll
    for (int ks = 0; ks < 4; ks++) {            // k = 256..383 (feat)
#pragma unroll
        for (int t = 0; t < 8; t++)
            acc1[t] = __builtin_amdgcn_mfma_f32_16x16x32_bf16(
                fa[ks], wb1[(8 + ks) * 512 + t * 16], acc1[t], 0, 0, 0);
    }

    // Staging reads all issued; safe to overwrite the region with lds_h.
    __syncthreads();

    // h = layer1 + b1 -> LDS (bf16): C-layout -> A-layout round trip.
    // lds_h row stride 136 shorts (272B = 17*16B: aligned, bank-padded).
    short* lh = reinterpret_cast<short*>(wbase);
#pragma unroll
    for (int t = 0; t < 8; t++) {
        const int col = t * 16 + m;
        const float bias = b1[col];
#pragma unroll
        for (int r = 0; r < 4; r++)
            lh[(quad * 4 + r) * 136 + col] = f2bf(acc1[t][r] + bias);
    }
    __syncthreads();

    floatx4 acc2[8];
#pragma unroll
    for (int t = 0; t < 8; t++) acc2[t] = zero4;
    const short8* wb2 = w2P + quad * 128 + m;
#pragma unroll
    for (int ks = 0; ks < 4; ks++) {
        const int k0 = ks * 32 + quad * 8;
        short8 ah = *reinterpret_cast<const short8*>(&lh[m * 136 + k0]);
#pragma unroll
        for (int t = 0; t < 8; t++)
            acc2[t] = __builtin_amdgcn_mfma_f32_16x16x32_bf16(
                ah, wb2[ks * 512 + t * 16], acc2[t], 0, 0, 0);
    }

    // bias2 + LayerNorm over each row's 128 cols
    float vals[8][4];
    float s1[4] = {0.f, 0.f, 0.f, 0.f}, s2[4] = {0.f, 0.f, 0.f, 0.f};
#pragma unroll
    for (int t = 0; t < 8; t++) {
        const float bias = b2[t * 16 + m];
#pragma unroll
        for (int r = 0; r < 4; r++) {
            float v = acc2[t][r] + bias;
            vals[t][r] = v; s1[r] += v; s2[r] += v * v;
        }
    }
#pragma unroll
    for (int off = 1; off < 16; off <<= 1) {
#pragma unroll
        for (int r = 0; r < 4; r++) {
            s1[r] += __shfl_xor(s1[r], off);
            s2[r] += __shfl_xor(s2[r], off);
        }
    }
    if (active) {
#pragma unroll
        for (int r = 0; r < 4; r++) {
            const float mu = s1[r] * (1.f / 128.f);
            const float var = s2[r] * (1.f / 128.f) - mu * mu;
            const float rstd = rsqrtf(var + 1e-5f);
            const int orow = row0 + quad * 4 + r;
#pragma unroll
            for (int t = 0; t < 8; t++) {
                const int col = t * 16 + m;
                out[(size_t)orow * 128 + col] =
                    (vals[t][r] - mu) * rstd * g[col] + bvec[col];
            }
        }
    }
}

extern "C" void kernel_launch(void* const* d_in, const int* in_sizes, int n_in,
                              void* d_out, int out_size, void* d_ws, size_t ws_size,
                              hipStream_t stream)
{
    const float* node_f = (const float*)d_in[0];
    const float* edge_f = (const float*)d_in[1];
    const int* senders   = (const int*)d_in[2];
    const int* receivers = (const int*)d_in[3];
    const float* nw1 = (const float*)d_in[4];
    const float* nb1 = (const float*)d_in[5];
    const float* nw2 = (const float*)d_in[6];
    const float* nb2 = (const float*)d_in[7];
    const float* ng  = (const float*)d_in[8];
    const float* nbb = (const float*)d_in[9];
    const float* ew1 = (const float*)d_in[10];
    const float* eb1 = (const float*)d_in[11];
    const float* ew2 = (const float*)d_in[12];
    const float* eb2 = (const float*)d_in[13];
    const float* eg  = (const float*)d_in[14];
    const float* ebb = (const float*)d_in[15];

    const int N = in_sizes[0] / 128;
    const int E = in_sizes[2];

    // ws layout (ints first): counts[N] | gctr[64] | startA[N] | cursor[N] |
    // eidx[E] | nodes_bf[N*128 bf16] | w1P | w2P.   ~14.7 MB total.
    char* ws = (char*)d_ws;
    int* counts = (int*)ws;
    int* gctr   = counts + N;
    int* startA = gctr + 64;
    int* cursor = startA + N;
    int* eidx   = cursor + N;
    size_t int_bytes = ((size_t)(3 * N + 64) + (size_t)E) * 4;
    int_bytes = (int_bytes + 15) & ~(size_t)15;          // 16B align
    short* nodes_bf = (short*)(ws + int_bytes);
    short* w1P = nodes_bf + (size_t)N * 128;
    short* w2P = w1P + 49152;

    float* out_nodes = (float*)d_out;
    float* out_edges = out_nodes + (size_t)N * 128;

    hipMemsetAsync(counts, 0, (size_t)(N + 64) * 4, stream);  // counts + gctr
    prep_weights<<<256, 256, 0, stream>>>(ew1, ew2, w1P, w2P);

    csr_hist<<<(E + 255) / 256, 256, 0, stream>>>(receivers, counts, E);
    csr_alloc<<<(N + 255) / 256, 256, 0, stream>>>(counts, startA, cursor, gctr, N);
    csr_fill<<<(E + 255) / 256, 256, 0, stream>>>(receivers, cursor, eidx, E);

    node_mlp_valu<<<(N + 31) / 32, 256, 0, stream>>>(
        node_f, edge_f, counts, startA, eidx,
        nw1, nb1, nw2, nb2, ng, nbb, out_nodes, nodes_bf, N);

    edge_mlp_mfma<<<(E + 63) / 64, 256, 0, stream>>>(
        edge_f, nodes_bf, senders, receivers,
        (const short8*)w1P, (const short8*)w2P,
        eb1, eb2, eg, ebb, out_edges, E);
}